// Round 1
// baseline (1460.018 us; speedup 1.0000x reference)
//
#include <hip/hip_runtime.h>

#define R_ 8
#define N_ 40000
#define F_ 128
#define E_ 160000
#define NE (R_ * E_)        // 1,280,000 edges
#define NBUK 625            // src>>6 buckets of 64 rows; 625*64 == 40000 exactly
#define CAP 2560            // bucket capacity: mean 2048, sigma ~45 -> 11 sigma headroom
#define FBLK 320            // edge bin chunks
#define FCHUNK 4000         // FBLK * FCHUNK == NE exactly
#define RELCHUNKS (E_ / FCHUNK)   // 40 chunks per relation -> chunk's relation is uniform

typedef unsigned short ushort;
typedef unsigned int uint;
typedef __attribute__((ext_vector_type(8))) short bf16x8;
typedef __attribute__((ext_vector_type(4))) float f32x4;

// fp32 -> bf16 round-to-nearest-even (returns bit pattern)
__device__ __forceinline__ ushort f2bf(float x) {
    uint u = __float_as_uint(x);
    return (ushort)((u + 0x7fffu + ((u >> 16) & 1u)) >> 16);
}

// --- K1: fused independent prep ---
// blocks [0,625):    proj = ent @ W  via bf16 MFMA (64 rows/block)   [unchanged]
// block  625:        rel_mat passthrough to out tail                  [unchanged]
// blocks [626,946):  binning — per-block redundant alpha MLP, then scatter
//                    edges into fixed-capacity 64-row buckets via global atomic ranks
__global__ __launch_bounds__(256) void fused_prep(
        const float* __restrict__ ent, const float* __restrict__ W,
        ushort* __restrict__ proj,
        const int* __restrict__ esrc, const int* __restrict__ edst,
        const float* __restrict__ eval_,
        const float* __restrict__ rel, float* __restrict__ out_tail,
        const float* __restrict__ w1, const float* __restrict__ b1,
        const float* __restrict__ w2,
        uint2* __restrict__ staged, int* __restrict__ count) {
    __shared__ float smem[64 * F_];          // 32 KB; GEMM aliases as ushort Wt[128][128]
    __shared__ float alpha_s[8];
    const int t = threadIdx.x;
    const int b = blockIdx.x;
    if (b < 625) {
        ushort* Wt = (ushort*)smem;          // W^T bf16, row n (col of W), chunk-XOR swizzle
#pragma unroll
        for (int p = 0; p < 16; ++p) {
            int k = p * 8 + (t >> 5);
            int c4 = (t & 31) * 4;
            float4 wvv = *(const float4*)&W[k * F_ + c4];
#pragma unroll
            for (int i = 0; i < 4; ++i) {
                int col = c4 + i;
                float v = (i == 0) ? wvv.x : (i == 1) ? wvv.y : (i == 2) ? wvv.z : wvv.w;
                Wt[col * F_ + ((((k >> 3) ^ (col & 7)) << 3) | (k & 7))] = f2bf(v);
            }
        }
        __syncthreads();
        const int wv_ = t >> 6;              // wave 0..3
        const int lane = t & 63;
        const int m = lane & 15;
        const int q = (lane >> 4) & 3;
        const int row0 = b * 64 + wv_ * 16;
        bf16x8 afrag[4];
        const float* arow = ent + (size_t)(row0 + m) * F_;
#pragma unroll
        for (int kc = 0; kc < 4; ++kc) {
            float4 a0 = *(const float4*)&arow[kc * 32 + q * 8];
            float4 a1 = *(const float4*)&arow[kc * 32 + q * 8 + 4];
            bf16x8 a;
            a[0] = (short)f2bf(a0.x); a[1] = (short)f2bf(a0.y);
            a[2] = (short)f2bf(a0.z); a[3] = (short)f2bf(a0.w);
            a[4] = (short)f2bf(a1.x); a[5] = (short)f2bf(a1.y);
            a[6] = (short)f2bf(a1.z); a[7] = (short)f2bf(a1.w);
            afrag[kc] = a;
        }
        f32x4 acc[8];
#pragma unroll
        for (int ct = 0; ct < 8; ++ct) acc[ct] = (f32x4){0.f, 0.f, 0.f, 0.f};
#pragma unroll
        for (int ct = 0; ct < 8; ++ct) {
            int n = ct * 16 + m;
#pragma unroll
            for (int kc = 0; kc < 4; ++kc) {
                int chunk = kc * 4 + q;
                bf16x8 bfrag = *(const bf16x8*)&Wt[n * F_ + ((chunk ^ (n & 7)) << 3)];
                acc[ct] = __builtin_amdgcn_mfma_f32_16x16x32_bf16(afrag[kc], bfrag, acc[ct], 0, 0, 0);
            }
        }
#pragma unroll
        for (int ct = 0; ct < 8; ++ct) {
#pragma unroll
            for (int reg = 0; reg < 4; ++reg) {
                int row = row0 + q * 4 + reg;
                proj[(size_t)row * F_ + ct * 16 + m] = f2bf(acc[ct][reg]);
            }
        }
    } else if (b == 625) {
        ((float4*)out_tail)[t] = ((const float4*)rel)[t];   // 1024 floats
    } else {
        // --- alpha MLP, all 8 relations, redundant per block (identical f-order to old) ---
        const int r = t >> 5;                // 0..7
        const int o = t & 31;
        float p0 = 0.f, p1 = 0.f, p2 = 0.f, p3 = 0.f;
        const float* relr = rel + r * F_;
        for (int f = 0; f < F_; ++f) {
            float rv = relr[f];
            const float* w1f = w1 + f * F_;
            p0 += rv * w1f[o];
            p1 += rv * w1f[o + 32];
            p2 += rv * w1f[o + 64];
            p3 += rv * w1f[o + 96];
        }
        float hs = tanhf(p0 + b1[o]) * w2[o]
                 + tanhf(p1 + b1[o + 32]) * w2[o + 32]
                 + tanhf(p2 + b1[o + 64]) * w2[o + 64]
                 + tanhf(p3 + b1[o + 96]) * w2[o + 96];
        smem[t] = hs;
        __syncthreads();
        for (int off = 16; off > 0; off >>= 1) {
            if (o < off) smem[t] += smem[t + off];
            __syncthreads();
        }
        if (o == 0) alpha_s[r] = 1.f / (1.f + expf(-smem[t]));
        __syncthreads();
        // --- bin this chunk's 4000 edges into buckets (global atomic ranks) ---
        const int hb = b - 626;
        const float av = alpha_s[hb / RELCHUNKS];   // chunk is entirely one relation
        const int base = hb * FCHUNK;
        for (int i = t; i < FCHUNK; i += 512) {     // 2 independent chains in flight
            int e0 = base + i;
            int sa = esrc[e0];
            uint xa = (uint)edst[e0] | ((uint)f2bf(av * eval_[e0]) << 16);
            int i1 = i + 256;
            int sb = 0; uint xb = 0;
            if (i1 < FCHUNK) {
                int e1 = base + i1;
                sb = esrc[e1];
                xb = (uint)edst[e1] | ((uint)f2bf(av * eval_[e1]) << 16);
            }
            int ra = atomicAdd(&count[sa >> 6], 1);
            if (ra < CAP) staged[(sa >> 6) * CAP + ra] = make_uint2(xa, (uint)(sa & 63));
            if (i1 < FCHUNK) {
                int rb = atomicAdd(&count[sb >> 6], 1);
                if (rb < CAP) staged[(sb >> 6) * CAP + rb] = make_uint2(xb, (uint)(sb & 63));
            }
        }
    }
}

// --- K2: bucket-accumulate SpMM — gather proj[dst] rows, ds_add_f32 into a
//         64x128 fp32 LDS tile, coalesced tile write. Replaces fillscan/bucketscan/
//         fillC + CSR spmm (no sorted[] round-trip, no rowptr). ---
__global__ __launch_bounds__(256) void spmm_agg(
        const uint2* __restrict__ staged, const int* __restrict__ count,
        const ushort* __restrict__ proj, float* __restrict__ out) {
    __shared__ float acc[64 * F_];           // 32 KB -> 4 blocks/CU, all 625 co-resident
    const int t = threadIdx.x;
    const int b = blockIdx.x;
    const int wv = t >> 6;
    const int lane = t & 63;
#pragma unroll
    for (int i = 0; i < 8; ++i)
        ((float4*)acc)[t + i * 256] = make_float4(0.f, 0.f, 0.f, 0.f);
    __syncthreads();
    int cnt = count[b];
    if (cnt > CAP) cnt = CAP;
    const uint2* seg = staged + (size_t)b * CAP;
    int per = (((cnt + 3) >> 2) + 1) & ~1;   // even -> uint4-aligned wave ranges
    int beg = wv * per;
    int end = beg + per;
    if (end > cnt) end = cnt;
    int j = beg;
    for (; j + 4 <= end; j += 4) {           // 4 gathers in flight per wave
        uint4 q0 = *(const uint4*)&seg[j];
        uint4 q1 = *(const uint4*)&seg[j + 2];
        uint u0 = *(const uint*)&proj[((q0.x & 0xffffu) << 7) + 2 * lane];
        uint u1 = *(const uint*)&proj[((q0.z & 0xffffu) << 7) + 2 * lane];
        uint u2 = *(const uint*)&proj[((q1.x & 0xffffu) << 7) + 2 * lane];
        uint u3 = *(const uint*)&proj[((q1.z & 0xffffu) << 7) + 2 * lane];
        float w0 = __uint_as_float(q0.x & 0xffff0000u);
        float w1 = __uint_as_float(q0.z & 0xffff0000u);
        float w2 = __uint_as_float(q1.x & 0xffff0000u);
        float w3 = __uint_as_float(q1.z & 0xffff0000u);
        int ro0 = (int)(q0.y & 63u) * F_ + 2 * lane;
        int ro1 = (int)(q0.w & 63u) * F_ + 2 * lane;
        int ro2 = (int)(q1.y & 63u) * F_ + 2 * lane;
        int ro3 = (int)(q1.w & 63u) * F_ + 2 * lane;
        atomicAdd(&acc[ro0],     w0 * __uint_as_float(u0 << 16));
        atomicAdd(&acc[ro0 + 1], w0 * __uint_as_float(u0 & 0xffff0000u));
        atomicAdd(&acc[ro1],     w1 * __uint_as_float(u1 << 16));
        atomicAdd(&acc[ro1 + 1], w1 * __uint_as_float(u1 & 0xffff0000u));
        atomicAdd(&acc[ro2],     w2 * __uint_as_float(u2 << 16));
        atomicAdd(&acc[ro2 + 1], w2 * __uint_as_float(u2 & 0xffff0000u));
        atomicAdd(&acc[ro3],     w3 * __uint_as_float(u3 << 16));
        atomicAdd(&acc[ro3 + 1], w3 * __uint_as_float(u3 & 0xffff0000u));
    }
    for (; j < end; ++j) {
        uint2 e = seg[j];
        uint u = *(const uint*)&proj[((e.x & 0xffffu) << 7) + 2 * lane];
        float w = __uint_as_float(e.x & 0xffff0000u);
        int ro = (int)(e.y & 63u) * F_ + 2 * lane;
        atomicAdd(&acc[ro],     w * __uint_as_float(u << 16));
        atomicAdd(&acc[ro + 1], w * __uint_as_float(u & 0xffff0000u));
    }
    __syncthreads();
    float* orow = out + (size_t)b * (64 * F_);
#pragma unroll
    for (int i = 0; i < 8; ++i)
        ((float4*)orow)[t + i * 256] = ((const float4*)acc)[t + i * 256];
}

extern "C" void kernel_launch(void* const* d_in, const int* in_sizes, int n_in,
                              void* d_out, int out_size, void* d_ws, size_t ws_size,
                              hipStream_t stream) {
    const float* ent   = (const float*)d_in[0];
    const float* rel   = (const float*)d_in[1];
    const int*   esrc  = (const int*)d_in[2];
    const int*   edst  = (const int*)d_in[3];
    const float* eval_ = (const float*)d_in[4];
    const float* went  = (const float*)d_in[5];
    const float* w1    = (const float*)d_in[6];
    const float* b1    = (const float*)d_in[7];
    const float* w2    = (const float*)d_in[8];

    float* out      = (float*)d_out;
    float* out_tail = out + (size_t)N_ * F_;

    char* ws = (char*)d_ws;
    size_t off = 0;
    ushort* proj   = (ushort*)(ws + off); off += (size_t)N_ * F_ * 2;        // 10.24 MB
    uint2*  staged = (uint2*)(ws + off);  off += (size_t)NBUK * CAP * 8;     // 12.80 MB
    int*    count  = (int*)(ws + off);    off += (size_t)NBUK * 4;           // 2.5 KB

    hipMemsetAsync(count, 0, (size_t)NBUK * sizeof(int), stream);
    fused_prep<<<946, 256, 0, stream>>>(ent, went, proj, esrc, edst, eval_,
                                        rel, out_tail, w1, b1, w2, staged, count);
    spmm_agg<<<NBUK, 256, 0, stream>>>(staged, count, proj, out);
}

// Round 2
// 171.197 us; speedup vs baseline: 8.5283x; 8.5283x over previous
//
#include <hip/hip_runtime.h>

#define R_ 8
#define N_ 40000
#define F_ 128
#define E_ 160000
#define NE (R_ * E_)        // 1,280,000 edges
#define NBUK 625            // src>>6 buckets of 64 rows; 625*64 == 40000 exactly
#define CAP 2560            // fixed bucket capacity: mean 2048, sigma ~45 -> +11 sigma
#define FBLK 320            // edge chunks
#define FCHUNK 4000         // FBLK * FCHUNK == NE exactly
#define RELCHUNKS (E_ / FCHUNK)   // 40 chunks per relation -> a chunk is single-relation

typedef unsigned short ushort;
typedef unsigned int uint;
typedef __attribute__((ext_vector_type(8))) short bf16x8;
typedef __attribute__((ext_vector_type(4))) float f32x4;

// fp32 -> bf16 round-to-nearest-even (returns bit pattern)
__device__ __forceinline__ ushort f2bf(float x) {
    uint u = __float_as_uint(x);
    return (ushort)((u + 0x7fffu + ((u >> 16) & 1u)) >> 16);
}

// --- K1: fused independent prep (proven round-0 structure) ---
// blocks [0,625):    proj = ent @ W  via bf16 MFMA (64 rows/block)
// block  625:        rel_mat passthrough to out tail
// blocks [626,630):  alpha MLP (2 relations/block)
// blocks [630,950):  fillA — per-chunk bucket histogram (625 buckets of 64 rows)
__global__ __launch_bounds__(256) void fused_prep(
        const float* __restrict__ ent, const float* __restrict__ W,
        ushort* __restrict__ proj,
        const int* __restrict__ esrc,
        const float* __restrict__ rel, float* __restrict__ out_tail,
        const float* __restrict__ w1, const float* __restrict__ b1,
        const float* __restrict__ w2, float* __restrict__ alpha,
        int* __restrict__ hist) {
    __shared__ float smem[64 * F_];          // 32 KB; proj aliases as ushort Wt[128][128]
    const int t = threadIdx.x;
    const int b = blockIdx.x;
    if (b < 625) {
        ushort* Wt = (ushort*)smem;          // W^T bf16, chunk-XOR swizzle
#pragma unroll
        for (int p = 0; p < 16; ++p) {
            int k = p * 8 + (t >> 5);
            int c4 = (t & 31) * 4;
            float4 wv = *(const float4*)&W[k * F_ + c4];
#pragma unroll
            for (int i = 0; i < 4; ++i) {
                int col = c4 + i;
                float v = (i == 0) ? wv.x : (i == 1) ? wv.y : (i == 2) ? wv.z : wv.w;
                Wt[col * F_ + ((((k >> 3) ^ (col & 7)) << 3) | (k & 7))] = f2bf(v);
            }
        }
        __syncthreads();
        const int wv_ = t >> 6;              // wave 0..3
        const int lane = t & 63;
        const int m = lane & 15;
        const int q = (lane >> 4) & 3;
        const int row0 = b * 64 + wv_ * 16;
        bf16x8 afrag[4];
        const float* arow = ent + (size_t)(row0 + m) * F_;
#pragma unroll
        for (int kc = 0; kc < 4; ++kc) {
            float4 a0 = *(const float4*)&arow[kc * 32 + q * 8];
            float4 a1 = *(const float4*)&arow[kc * 32 + q * 8 + 4];
            bf16x8 a;
            a[0] = (short)f2bf(a0.x); a[1] = (short)f2bf(a0.y);
            a[2] = (short)f2bf(a0.z); a[3] = (short)f2bf(a0.w);
            a[4] = (short)f2bf(a1.x); a[5] = (short)f2bf(a1.y);
            a[6] = (short)f2bf(a1.z); a[7] = (short)f2bf(a1.w);
            afrag[kc] = a;
        }
        f32x4 acc[8];
#pragma unroll
        for (int ct = 0; ct < 8; ++ct) acc[ct] = (f32x4){0.f, 0.f, 0.f, 0.f};
#pragma unroll
        for (int ct = 0; ct < 8; ++ct) {
            int n = ct * 16 + m;
#pragma unroll
            for (int kc = 0; kc < 4; ++kc) {
                int chunk = kc * 4 + q;
                bf16x8 bfrag = *(const bf16x8*)&Wt[n * F_ + ((chunk ^ (n & 7)) << 3)];
                acc[ct] = __builtin_amdgcn_mfma_f32_16x16x32_bf16(afrag[kc], bfrag, acc[ct], 0, 0, 0);
            }
        }
#pragma unroll
        for (int ct = 0; ct < 8; ++ct) {
#pragma unroll
            for (int reg = 0; reg < 4; ++reg) {
                int row = row0 + q * 4 + reg;
                proj[(size_t)row * F_ + ct * 16 + m] = f2bf(acc[ct][reg]);
            }
        }
    } else if (b == 625) {
        ((float4*)out_tail)[t] = ((const float4*)rel)[t];   // 1024 floats
    } else if (b < 630) {
        int r = (b - 626) * 2 + (t >> 7);
        int o = t & 127;
        float s = 0.f;
#pragma unroll 8
        for (int f = 0; f < F_; ++f) s += rel[r * F_ + f] * w1[f * F_ + o];
        float h = tanhf(s + b1[o]);
        smem[t] = h * w2[o];
        __syncthreads();
        for (int off = 64; off > 0; off >>= 1) {
            if ((t & 127) < off) smem[t] += smem[t + off];
            __syncthreads();
        }
        if ((t & 127) == 0) alpha[r] = 1.f / (1.f + expf(-smem[t]));
    } else {
        // fillA: bucket histogram for chunk hb (LDS int atomics, contention-free-ish)
        int hb = b - 630;
        int* h = (int*)smem;
        for (int i = t; i < NBUK; i += 256) h[i] = 0;
        __syncthreads();
        int base = hb * FCHUNK;
        for (int i = t; i < FCHUNK; i += 256)
            atomicAdd(&h[esrc[base + i] >> 6], 1);
        __syncthreads();
        for (int i = t; i < NBUK; i += 256) hist[hb * NBUK + i] = h[i];
    }
}

// --- K2: per bucket, exclusive-scan the FBLK chunk counts (bucket-relative) + total ---
__global__ __launch_bounds__(FBLK) void fillscan_kernel(const int* __restrict__ hist,
                                                        int* __restrict__ blockbase,
                                                        int* __restrict__ total) {
    __shared__ int sc[FBLK];
    int b = blockIdx.x, t = threadIdx.x;
    int own = hist[t * NBUK + b];
    sc[t] = own;
    __syncthreads();
    for (int off = 1; off < FBLK; off <<= 1) {
        int v = (t >= off) ? sc[t - off] : 0;
        __syncthreads();
        sc[t] += v;
        __syncthreads();
    }
    blockbase[b * FBLK + t] = sc[t] - own;     // exclusive, bucket-relative
    if (t == FBLK - 1) total[b] = sc[t];
}

// --- K3: fillB — stage edges bucket-ordered; bucket base is STATIC (b*CAP) ---
__global__ __launch_bounds__(256) void fillB_kernel(const int* __restrict__ esrc,
                                                    const int* __restrict__ edst,
                                                    const float* __restrict__ eval_,
                                                    const float* __restrict__ alpha,
                                                    const int* __restrict__ blockbase,
                                                    uint2* __restrict__ staged) {
    __shared__ int lcnt[NBUK];
    __shared__ int lbase[NBUK];
    int t = threadIdx.x, blk = blockIdx.x;
    for (int i = t; i < NBUK; i += 256) {
        lcnt[i] = 0;
        lbase[i] = i * CAP + blockbase[i * FBLK + blk];
    }
    __syncthreads();
    const float av = alpha[blk / RELCHUNKS];   // chunk is entirely one relation
    int base = blk * FCHUNK;
    for (int i = t; i < FCHUNK; i += 256) {
        int e = base + i;
        int s = esrc[e];
        int d = edst[e];
        float w = av * eval_[e];
        int bk = s >> 6;
        int rank = atomicAdd(&lcnt[bk], 1);
        int pos = lbase[bk] + rank;
        if (pos < (bk + 1) * CAP)              // statistical overflow guard
            staged[pos] = make_uint2((uint)d | ((uint)f2bf(w) << 16), (uint)s);
    }
}

// --- K4: fillC+spmm fused — in-LDS count-sort of the bucket, then register-
//         accumulating wave-per-row spmm straight out of LDS (no sorted[] /
//         rowptr round-trip, no fp32 atomics anywhere) ---
__global__ __launch_bounds__(512) void fillC_spmm(const uint2* __restrict__ staged,
                                                  const int* __restrict__ total,
                                                  const ushort* __restrict__ proj,
                                                  float* __restrict__ out) {
    __shared__ uint2 raw[CAP];       // 20 KB
    __shared__ uint  srt[CAP];       // 10 KB
    __shared__ int cnt[64], cur[64], rs[65];
    const int b = blockIdx.x, t = threadIdx.x;
    int n = total[b];
    if (n > CAP) n = CAP;
    if (t < 64) cnt[t] = 0;
    __syncthreads();
    const uint2* seg = staged + (size_t)b * CAP;
    for (int i = t; i < n; i += 512) {
        uint2 e = seg[i];
        raw[i] = e;
        atomicAdd(&cnt[e.y & 63], 1);
    }
    __syncthreads();
    if (t < 64) cur[t] = cnt[t];
    __syncthreads();
    for (int off = 1; off < 64; off <<= 1) {
        int v = (t < 64 && t >= off) ? cur[t - off] : 0;
        __syncthreads();
        if (t < 64) cur[t] += v;
        __syncthreads();
    }
    if (t < 64) {
        rs[t + 1] = cur[t];                    // inclusive -> row end
        if (t == 0) rs[0] = 0;
        cur[t] -= cnt[t];                      // exclusive row start
    }
    __syncthreads();
    for (int i = t; i < n; i += 512) {
        uint2 e = raw[i];
        int pos = atomicAdd(&cur[e.y & 63], 1);
        srt[pos] = e.x;
    }
    __syncthreads();
    // spmm: 8 waves, wave w owns rows w*8 .. w*8+7
    const int wv = t >> 6;
    const int lane = t & 63;
    for (int rr = 0; rr < 8; ++rr) {
        int r = wv * 8 + rr;
        int beg = rs[r], end = rs[r + 1];
        float accx = 0.f, accy = 0.f;
        int j = beg;
        for (; j + 4 <= end; j += 4) {
            uint e0 = srt[j], e1 = srt[j + 1], e2 = srt[j + 2], e3 = srt[j + 3];
            uint u0 = *(const uint*)&proj[((e0 & 0xffffu) << 7) + 2 * lane];
            uint u1 = *(const uint*)&proj[((e1 & 0xffffu) << 7) + 2 * lane];
            uint u2 = *(const uint*)&proj[((e2 & 0xffffu) << 7) + 2 * lane];
            uint u3 = *(const uint*)&proj[((e3 & 0xffffu) << 7) + 2 * lane];
            float w0 = __uint_as_float(e0 & 0xffff0000u);
            float w1 = __uint_as_float(e1 & 0xffff0000u);
            float w2 = __uint_as_float(e2 & 0xffff0000u);
            float w3 = __uint_as_float(e3 & 0xffff0000u);
            accx += w0 * __uint_as_float(u0 << 16);
            accy += w0 * __uint_as_float(u0 & 0xffff0000u);
            accx += w1 * __uint_as_float(u1 << 16);
            accy += w1 * __uint_as_float(u1 & 0xffff0000u);
            accx += w2 * __uint_as_float(u2 << 16);
            accy += w2 * __uint_as_float(u2 & 0xffff0000u);
            accx += w3 * __uint_as_float(u3 << 16);
            accy += w3 * __uint_as_float(u3 & 0xffff0000u);
        }
        for (; j < end; ++j) {
            uint e = srt[j];
            uint u = *(const uint*)&proj[((e & 0xffffu) << 7) + 2 * lane];
            float w = __uint_as_float(e & 0xffff0000u);
            accx += w * __uint_as_float(u << 16);
            accy += w * __uint_as_float(u & 0xffff0000u);
        }
        *(float2*)&out[(((size_t)b * 64 + r) << 7) + 2 * lane] = make_float2(accx, accy);
    }
}

extern "C" void kernel_launch(void* const* d_in, const int* in_sizes, int n_in,
                              void* d_out, int out_size, void* d_ws, size_t ws_size,
                              hipStream_t stream) {
    const float* ent   = (const float*)d_in[0];
    const float* rel   = (const float*)d_in[1];
    const int*   esrc  = (const int*)d_in[2];
    const int*   edst  = (const int*)d_in[3];
    const float* eval_ = (const float*)d_in[4];
    const float* went  = (const float*)d_in[5];
    const float* w1    = (const float*)d_in[6];
    const float* b1    = (const float*)d_in[7];
    const float* w2    = (const float*)d_in[8];

    float* out      = (float*)d_out;
    float* out_tail = out + (size_t)N_ * F_;

    char* ws = (char*)d_ws;
    size_t off = 0;
    ushort* proj      = (ushort*)(ws + off); off += (size_t)N_ * F_ * 2;       // 10.24 MB
    uint2*  staged    = (uint2*)(ws + off);  off += (size_t)NBUK * CAP * 8;    // 12.80 MB
    float*  alpha     = (float*)(ws + off);  off += 256;
    int*    hist      = (int*)(ws + off);    off += (size_t)FBLK * NBUK * 4;   // 800 KB
    int*    blockbase = (int*)(ws + off);    off += (size_t)NBUK * FBLK * 4;   // 800 KB
    int*    total     = (int*)(ws + off);    off += (size_t)(NBUK + 7) * 4;

    fused_prep<<<950, 256, 0, stream>>>(ent, went, proj, esrc,
                                        rel, out_tail, w1, b1, w2, alpha, hist);
    fillscan_kernel<<<NBUK, FBLK, 0, stream>>>(hist, blockbase, total);
    fillB_kernel<<<FBLK, 256, 0, stream>>>(esrc, edst, eval_, alpha, blockbase, staged);
    fillC_spmm<<<NBUK, 512, 0, stream>>>(staged, total, proj, out);
}